// Round 15
// baseline (222.067 us; speedup 1.0000x reference)
//
#include <hip/hip_runtime.h>
#include <hip/hip_bf16.h>
#include <stdint.h>

typedef short short8 __attribute__((ext_vector_type(8)));
typedef float f32x4 __attribute__((ext_vector_type(4)));
typedef unsigned int u32;
typedef unsigned short u16;

#define HH 512
#define WW 512
#define CC 64
#define PLANE (HH*WW)
#define NSTATF 524288.0f

// conv geometry (16x16x32, 2-row X-reuse, NSLOT 6)
#define KTW 32
#define HSTR1 560
#define KBSTR1 1120
#define SLOTB1 4480
#define NSLOT 6
#define RING1 (NSLOT*SLOTB1)  // 26880
#define BOUNCE 8192           // 2 rows x 4KB
#define NBC1 1024
#define K5S 132

__device__ __forceinline__ u16 f2bf(float f) {
  __hip_bfloat16 h = __float2bfloat16(f);
  return __builtin_bit_cast(u16, h);
}
__device__ __forceinline__ u32 pk2bf(float a, float b) {
  return (u32)f2bf(a) | ((u32)f2bf(b) << 16);
}
__device__ __forceinline__ float bf2f(u16 u) {
  u32 x = ((u32)u) << 16;
  return __builtin_bit_cast(float, x);
}
__device__ __forceinline__ int m6(int v) {  // v in [0,17] -> v % 6
  v -= (v >= 6) ? 6 : 0;
  v -= (v >= 6) ? 6 : 0;
  return v;
}
// barrier that makes LDS writes visible without draining vmcnt (T4)
__device__ __forceinline__ void lds_barrier() {
  asm volatile("s_waitcnt lgkmcnt(0)" ::: "memory");
  __builtin_amdgcn_s_barrier();
  __builtin_amdgcn_sched_barrier(0);
}

// ---------------- kprep: 16x16x32 fragment layouts for w1, w2, wp ----------------
__global__ __launch_bounds__(512) void kprep(const float* __restrict__ w1,
    const float* __restrict__ w2, const float* __restrict__ wp,
    u16* __restrict__ wb1, u16* __restrict__ wb2, u16* __restrict__ wbp)
{
  const int id = blockIdx.x*512 + threadIdx.x;
  const int lane = id & 63;
  if (id < 9216) {
    const float* w = (id < 4608) ? w1 : w2;
    u16* o = (id < 4608) ? wb1 : wb2;
    const int fid = (id < 4608) ? (id >> 6) : ((id - 4608) >> 6);  // 0..71
    const int ct4 = fid / 18, rem = fid % 18;
    const int tap = rem >> 1, kb = rem & 1;
    const int cout = ct4*16 + (lane & 15);
    const int k0c = kb*32 + (lane >> 4)*8;
    u32 ow[4];
#pragma unroll
    for (int p = 0; p < 4; ++p) {
      ow[p] = pk2bf(w[(size_t)(cout*64 + k0c + p*2)*9 + tap],
                    w[(size_t)(cout*64 + k0c + p*2 + 1)*9 + tap]);
    }
    *(uint4*)(o + ((size_t)fid*64 + lane)*8) = make_uint4(ow[0],ow[1],ow[2],ow[3]);
  } else if (id < 9728) {
    const int fid = (id - 9216) >> 6;     // 0..7
    const int ct4 = fid >> 1, kb = fid & 1;
    const int cout = ct4*16 + (lane & 15);
    const int k0c = kb*32 + (lane >> 4)*8;
    u32 ow[4];
#pragma unroll
    for (int p = 0; p < 4; ++p)
      ow[p] = pk2bf(wp[cout*64 + k0c + p*2], wp[cout*64 + k0c + p*2 + 1]);
    *(uint4*)(wbp + ((size_t)fid*64 + lane)*8) = make_uint4(ow[0],ow[1],ow[2],ow[3]);
  }
}

// ---------------- k0: pure NCHW fp32 -> NHWC bf16 transpose ----------------
__global__ __launch_bounds__(256) void k0(const float* __restrict__ x, u16* __restrict__ xh)
{
  __shared__ __align__(16) u32 Tp[32*260];
  const int tid = threadIdx.x;
  const int wt = blockIdx.x, h = blockIdx.y, n = blockIdx.z;
  const int w0 = wt*256;
  const float* xp = x + (size_t)n*CC*PLANE + (size_t)h*WW + w0;
#pragma unroll
  for (int it = 0; it < 8; ++it) {
    const int j = it*256 + tid;
    const int c2 = j >> 6, w4 = (j & 63) << 2;
    const f32x4 a = *(const f32x4*)(xp + (size_t)(c2*2    )*PLANE + w4);
    const f32x4 b = *(const f32x4*)(xp + (size_t)(c2*2 + 1)*PLANE + w4);
    uint4 o;
    o.x = pk2bf(a[0], b[0]);
    o.y = pk2bf(a[1], b[1]);
    o.z = pk2bf(a[2], b[2]);
    o.w = pk2bf(a[3], b[3]);
    *(uint4*)(Tp + (u32)c2*260 + (u32)(w4 ^ (4*(c2 >> 2)))) = o;
  }
  __syncthreads();
  u16* op = xh + ((size_t)(n*HH + h)*WW + w0)*CC;
#pragma unroll
  for (int it = 0; it < 8; ++it) {
    const int j = it*256 + tid;
    const int w = j >> 3, c8 = j & 7;
    const u32 wsw = (u32)(w ^ (4*c8));
    uint4 o;
    o.x = Tp[(u32)(c8*4 + 0)*260 + wsw];
    o.y = Tp[(u32)(c8*4 + 1)*260 + wsw];
    o.z = Tp[(u32)(c8*4 + 2)*260 + wsw];
    o.w = Tp[(u32)(c8*4 + 3)*260 + wsw];
    *(uint4*)(op + (size_t)w*CC + c8*8) = o;
  }
}

// ---------------- kconv1: 3x3 conv (y1 out) + proj MFMA for STATS ONLY ----------------
__global__ __launch_bounds__(256, 2) void kconv1(const u16* __restrict__ in,
    const u16* __restrict__ wb, const u16* __restrict__ wbp,
    u16* __restrict__ out,
    float* __restrict__ ps, float* __restrict__ pq,
    float* __restrict__ psp, float* __restrict__ pqp)
{
  __shared__ __align__(16) char LB[RING1 + BOUNCE + 512];
  const int tid = threadIdx.x;
  const int lane = tid & 63, wv = tid >> 6;
  const int l15 = lane & 15, lq = lane >> 4;
  const int wt = blockIdx.x, hs = blockIdx.y, n = blockIdx.z;
  const int w0 = wt*KTW, h0 = hs*16;
  const int bid = (n*32 + hs)*16 + wt;

  short8 wfr[18];
#pragma unroll
  for (int f = 0; f < 18; ++f)
    wfr[f] = *(const short8*)(wb + ((size_t)(wv*18 + f)*64 + lane)*8);
  short8 wpf[2];
#pragma unroll
  for (int kb = 0; kb < 2; ++kb)
    wpf[kb] = *(const short8*)(wbp + ((size_t)(wv*2 + kb)*64 + lane)*8);

  float s4[4] = {0,0,0,0}, q4[4] = {0,0,0,0};
  float sp4[4] = {0,0,0,0}, qp4[4] = {0,0,0,0};
  const u16* inb = in + (size_t)n*PLANE*CC;
  const u32 co0 = (u32)((lq >> 1)*KBSTR1 + (lq & 1)*HSTR1);
  const u32 co1 = co0 + 2*KBSTR1;

  auto ld_one = [&](int j, int cl, int c8) -> uint4 {
    const int gh = h0 - 1 + j, gw = w0 - 1 + cl;
    if (((u32)gh < (u32)HH) && ((u32)gw < (u32)WW))
      return *(const uint4*)(inb + ((size_t)gh*WW + gw)*CC + c8*8);
    return make_uint4(0u,0u,0u,0u);
  };
  auto st_one = [&](int slot, int cl, int c8, uint4 v) {
    *(uint4*)(LB + (size_t)slot*SLOTB1 + (c8>>1)*KBSTR1 + (c8&1)*HSTR1 + cl*16) = v;
  };

  for (int idx = tid; idx < 4*272; idx += 256) {
    const int jj = idx / 272, rem = idx - jj*272;
    st_one(jj, rem >> 3, rem & 7, ld_one(jj, rem >> 3, rem & 7));
  }
  __syncthreads();

  uint4 st0, st1, st2;
  auto issue2 = [&](int jb) {
    { const int idx = tid;       const int jj = idx/272, rem = idx - jj*272;
      st0 = ld_one(jb + jj, rem >> 3, rem & 7); }
    { const int idx = 256 + tid; const int jj = idx/272, rem = idx - jj*272;
      st1 = ld_one(jb + jj, rem >> 3, rem & 7); }
    if (tid < 32) { const int idx = 512 + tid; const int jj = idx/272, rem = idx - jj*272;
      st2 = ld_one(jb + jj, rem >> 3, rem & 7); }
  };
  auto write2 = [&](int jb) {
    { const int idx = tid;       const int jj = idx/272, rem = idx - jj*272;
      st_one(m6(jb + jj), rem >> 3, rem & 7, st0); }
    { const int idx = 256 + tid; const int jj = idx/272, rem = idx - jj*272;
      st_one(m6(jb + jj), rem >> 3, rem & 7, st1); }
    if (tid < 32) { const int idx = 512 + tid; const int jj = idx/272, rem = idx - jj*272;
      st_one(m6(jb + jj), rem >> 3, rem & 7, st2); }
  };

  issue2(4);

  for (int g = 0; g < 8; ++g) {
    if (g > 0) write2(2*g + 2);
    lds_barrier();
    if (g < 7) issue2(2*g + 4);

    const char* sb[4];
#pragma unroll
    for (int mi = 0; mi < 4; ++mi)
      sb[mi] = LB + (size_t)m6(2*g + mi)*SLOTB1 + l15*16;
    f32x4 a0t0, a0t1, a1t0, a1t1;
    f32x4 p0t0, p0t1, p1t0, p1t1;
#pragma unroll
    for (int r = 0; r < 4; ++r) {
      a0t0[r]=0.f; a0t1[r]=0.f; a1t0[r]=0.f; a1t1[r]=0.f;
      p0t0[r]=0.f; p0t1[r]=0.f; p1t0[r]=0.f; p1t1[r]=0.f;
    }
#pragma unroll
    for (int t = 0; t < 2; ++t) {
      const int pb = t*16;
#pragma unroll
      for (int kb = 0; kb < 2; ++kb) {
        const u32 ck = kb ? co1 : co0;
#pragma unroll
        for (int mi = 0; mi < 4; ++mi) {
#pragma unroll
          for (int kw = 0; kw < 3; ++kw) {
            const short8 X = *(const short8*)(sb[mi] + ck + (u32)((pb + kw)*16));
            if (mi <= 2) {
              const short8 Wf = wfr[(mi*3 + kw)*2 + kb];
              if (t == 0) a0t0 = __builtin_amdgcn_mfma_f32_16x16x32_bf16(Wf, X, a0t0, 0,0,0);
              else        a0t1 = __builtin_amdgcn_mfma_f32_16x16x32_bf16(Wf, X, a0t1, 0,0,0);
            }
            if (mi >= 1) {
              const short8 Wf = wfr[((mi-1)*3 + kw)*2 + kb];
              if (t == 0) a1t0 = __builtin_amdgcn_mfma_f32_16x16x32_bf16(Wf, X, a1t0, 0,0,0);
              else        a1t1 = __builtin_amdgcn_mfma_f32_16x16x32_bf16(Wf, X, a1t1, 0,0,0);
            }
            if (kw == 1 && mi == 1) {
              if (t == 0) p0t0 = __builtin_amdgcn_mfma_f32_16x16x32_bf16(wpf[kb], X, p0t0, 0,0,0);
              else        p0t1 = __builtin_amdgcn_mfma_f32_16x16x32_bf16(wpf[kb], X, p0t1, 0,0,0);
            }
            if (kw == 1 && mi == 2) {
              if (t == 0) p1t0 = __builtin_amdgcn_mfma_f32_16x16x32_bf16(wpf[kb], X, p1t0, 0,0,0);
              else        p1t1 = __builtin_amdgcn_mfma_f32_16x16x32_bf16(wpf[kb], X, p1t1, 0,0,0);
            }
          }
        }
      }
    }
    {
      const int co = wv*16 + lq*4;
#pragma unroll
      for (int r = 0; r < 4; ++r) {
        s4[r] += a0t0[r] + a0t1[r] + a1t0[r] + a1t1[r];
        q4[r] = fmaf(a0t0[r], a0t0[r], q4[r]);
        q4[r] = fmaf(a0t1[r], a0t1[r], q4[r]);
        q4[r] = fmaf(a1t0[r], a1t0[r], q4[r]);
        q4[r] = fmaf(a1t1[r], a1t1[r], q4[r]);
        sp4[r] += p0t0[r] + p0t1[r] + p1t0[r] + p1t1[r];
        qp4[r] = fmaf(p0t0[r], p0t0[r], qp4[r]);
        qp4[r] = fmaf(p0t1[r], p0t1[r], qp4[r]);
        qp4[r] = fmaf(p1t0[r], p1t0[r], qp4[r]);
        qp4[r] = fmaf(p1t1[r], p1t1[r], qp4[r]);
      }
#pragma unroll
      for (int t = 0; t < 2; ++t) {
        const int pos = t*16 + l15;
        const u32 addr = ((u32)(pos*128 + co*2)) ^ (((u32)(pos & 7)) << 4);
        uint2 c0, c1;
        if (t == 0) {
          c0.x = pk2bf(a0t0[0], a0t0[1]); c0.y = pk2bf(a0t0[2], a0t0[3]);
          c1.x = pk2bf(a1t0[0], a1t0[1]); c1.y = pk2bf(a1t0[2], a1t0[3]);
        } else {
          c0.x = pk2bf(a0t1[0], a0t1[1]); c0.y = pk2bf(a0t1[2], a0t1[3]);
          c1.x = pk2bf(a1t1[0], a1t1[1]); c1.y = pk2bf(a1t1[2], a1t1[3]);
        }
        *(uint2*)(LB + RING1 + 0*4096 + addr) = c0;
        *(uint2*)(LB + RING1 + 1*4096 + addr) = c1;
      }
    }
    lds_barrier();
    {
      const int rowi = tid >> 7, tt = tid & 127;
      const int pos = tt >> 2, qb = (tt & 3)*32;
      const char* bb = LB + RING1 + rowi*4096;
      const u32 a0 = ((u32)(pos*128 + qb)) ^ (((u32)(pos & 7)) << 4);
      const uint4 v0 = *(const uint4*)(bb + a0);
      const uint4 v1 = *(const uint4*)(bb + (a0 ^ 16u));
      char* dst = (char*)out + ((size_t)((n*HH + h0 + 2*g + rowi)*WW + w0 + pos))*128 + qb;
      *(uint4*)dst = v0;
      *(uint4*)(dst + 16) = v1;
    }
  }

#pragma unroll
  for (int d = 1; d <= 8; d <<= 1) {
#pragma unroll
    for (int r = 0; r < 4; ++r) {
      s4[r] += __shfl_xor(s4[r], d, 64);
      q4[r] += __shfl_xor(q4[r], d, 64);
      sp4[r] += __shfl_xor(sp4[r], d, 64);
      qp4[r] += __shfl_xor(qp4[r], d, 64);
    }
  }
  if (l15 == 0) {
#pragma unroll
    for (int r = 0; r < 4; ++r) {
      const int co = wv*16 + lq*4 + r;
      ps[(size_t)co*NBC1 + bid] = s4[r];
      pq[(size_t)co*NBC1 + bid] = q4[r];
      psp[(size_t)co*NBC1 + bid] = sp4[r];
      pqp[(size_t)co*NBC1 + bid] = qp4[r];
    }
  }
}

// ---------------- kconv2: 3x3 conv, 16x16x32, 2-row X-reuse, BN1+ReLU on staging ----------------
__global__ __launch_bounds__(256, 2) void kconv2(const u16* __restrict__ in,
    const u16* __restrict__ wb,
    const float* __restrict__ As, const float* __restrict__ Bs,
    u16* __restrict__ out, float* __restrict__ ps, float* __restrict__ pq)
{
  __shared__ __align__(16) char LB[RING1 + BOUNCE + 512];
  float* sA = (float*)(LB + RING1 + BOUNCE);
  float* sB = sA + 64;
  const int tid = threadIdx.x;
  const int lane = tid & 63, wv = tid >> 6;
  const int l15 = lane & 15, lq = lane >> 4;
  const int wt = blockIdx.x, hs = blockIdx.y, n = blockIdx.z;
  const int w0 = wt*KTW, h0 = hs*16;
  const int bid = (n*32 + hs)*16 + wt;

  if (tid < 64) { sA[tid] = As[tid]; sB[tid] = Bs[tid]; }
  __syncthreads();

  short8 wfr[18];
#pragma unroll
  for (int f = 0; f < 18; ++f)
    wfr[f] = *(const short8*)(wb + ((size_t)(wv*18 + f)*64 + lane)*8);

  float s4[4] = {0,0,0,0}, q4[4] = {0,0,0,0};
  const u16* inb = in + (size_t)n*PLANE*CC;
  const u32 co0 = (u32)((lq >> 1)*KBSTR1 + (lq & 1)*HSTR1);
  const u32 co1 = co0 + 2*KBSTR1;

  auto ld_one = [&](int j, int cl, int c8) -> uint4 {
    const int gh = h0 - 1 + j, gw = w0 - 1 + cl;
    if (((u32)gh < (u32)HH) && ((u32)gw < (u32)WW))
      return *(const uint4*)(inb + ((size_t)gh*WW + gw)*CC + c8*8);
    return make_uint4(0u,0u,0u,0u);
  };
  auto st_one = [&](int slot, int cl, int c8, uint4 v) {
    const u32* uw = (const u32*)&v;
    u32 ow[4];
    const int cb = c8*8;
#pragma unroll
    for (int h2 = 0; h2 < 4; ++h2) {
      float f0 = fmaxf(bf2f((u16)(uw[h2] & 0xFFFFu)) * sA[cb+h2*2]   + sB[cb+h2*2],   0.f);
      float f1 = fmaxf(bf2f((u16)(uw[h2] >> 16))     * sA[cb+h2*2+1] + sB[cb+h2*2+1], 0.f);
      ow[h2] = pk2bf(f0, f1);
    }
    *(uint4*)(LB + (size_t)slot*SLOTB1 + (c8>>1)*KBSTR1 + (c8&1)*HSTR1 + cl*16) =
        make_uint4(ow[0],ow[1],ow[2],ow[3]);
  };

  for (int idx = tid; idx < 4*272; idx += 256) {
    const int jj = idx / 272, rem = idx - jj*272;
    st_one(jj, rem >> 3, rem & 7, ld_one(jj, rem >> 3, rem & 7));
  }
  __syncthreads();

  uint4 st0, st1, st2;
  auto issue2 = [&](int jb) {
    { const int idx = tid;       const int jj = idx/272, rem = idx - jj*272;
      st0 = ld_one(jb + jj, rem >> 3, rem & 7); }
    { const int idx = 256 + tid; const int jj = idx/272, rem = idx - jj*272;
      st1 = ld_one(jb + jj, rem >> 3, rem & 7); }
    if (tid < 32) { const int idx = 512 + tid; const int jj = idx/272, rem = idx - jj*272;
      st2 = ld_one(jb + jj, rem >> 3, rem & 7); }
  };
  auto write2 = [&](int jb) {
    { const int idx = tid;       const int jj = idx/272, rem = idx - jj*272;
      st_one(m6(jb + jj), rem >> 3, rem & 7, st0); }
    { const int idx = 256 + tid; const int jj = idx/272, rem = idx - jj*272;
      st_one(m6(jb + jj), rem >> 3, rem & 7, st1); }
    if (tid < 32) { const int idx = 512 + tid; const int jj = idx/272, rem = idx - jj*272;
      st_one(m6(jb + jj), rem >> 3, rem & 7, st2); }
  };

  issue2(4);

  for (int g = 0; g < 8; ++g) {
    if (g > 0) write2(2*g + 2);
    lds_barrier();
    if (g < 7) issue2(2*g + 4);

    const char* sb[4];
#pragma unroll
    for (int mi = 0; mi < 4; ++mi)
      sb[mi] = LB + (size_t)m6(2*g + mi)*SLOTB1 + l15*16;
    f32x4 a0t0, a0t1, a1t0, a1t1;
#pragma unroll
    for (int r = 0; r < 4; ++r) { a0t0[r]=0.f; a0t1[r]=0.f; a1t0[r]=0.f; a1t1[r]=0.f; }
#pragma unroll
    for (int t = 0; t < 2; ++t) {
      const int pb = t*16;
#pragma unroll
      for (int kb = 0; kb < 2; ++kb) {
        const u32 ck = kb ? co1 : co0;
#pragma unroll
        for (int mi = 0; mi < 4; ++mi) {
#pragma unroll
          for (int kw = 0; kw < 3; ++kw) {
            const short8 X = *(const short8*)(sb[mi] + ck + (u32)((pb + kw)*16));
            if (mi <= 2) {
              const short8 Wf = wfr[(mi*3 + kw)*2 + kb];
              if (t == 0) a0t0 = __builtin_amdgcn_mfma_f32_16x16x32_bf16(Wf, X, a0t0, 0,0,0);
              else        a0t1 = __builtin_amdgcn_mfma_f32_16x16x32_bf16(Wf, X, a0t1, 0,0,0);
            }
            if (mi >= 1) {
              const short8 Wf = wfr[((mi-1)*3 + kw)*2 + kb];
              if (t == 0) a1t0 = __builtin_amdgcn_mfma_f32_16x16x32_bf16(Wf, X, a1t0, 0,0,0);
              else        a1t1 = __builtin_amdgcn_mfma_f32_16x16x32_bf16(Wf, X, a1t1, 0,0,0);
            }
          }
        }
      }
    }
    {
      const int co = wv*16 + lq*4;
#pragma unroll
      for (int r = 0; r < 4; ++r) {
        s4[r] += a0t0[r] + a0t1[r] + a1t0[r] + a1t1[r];
        q4[r] = fmaf(a0t0[r], a0t0[r], q4[r]);
        q4[r] = fmaf(a0t1[r], a0t1[r], q4[r]);
        q4[r] = fmaf(a1t0[r], a1t0[r], q4[r]);
        q4[r] = fmaf(a1t1[r], a1t1[r], q4[r]);
      }
#pragma unroll
      for (int t = 0; t < 2; ++t) {
        const int pos = t*16 + l15;
        const u32 addr = ((u32)(pos*128 + co*2)) ^ (((u32)(pos & 7)) << 4);
        uint2 c0, c1;
        if (t == 0) {
          c0.x = pk2bf(a0t0[0], a0t0[1]); c0.y = pk2bf(a0t0[2], a0t0[3]);
          c1.x = pk2bf(a1t0[0], a1t0[1]); c1.y = pk2bf(a1t0[2], a1t0[3]);
        } else {
          c0.x = pk2bf(a0t1[0], a0t1[1]); c0.y = pk2bf(a0t1[2], a0t1[3]);
          c1.x = pk2bf(a1t1[0], a1t1[1]); c1.y = pk2bf(a1t1[2], a1t1[3]);
        }
        *(uint2*)(LB + RING1 + 0*4096 + addr) = c0;
        *(uint2*)(LB + RING1 + 1*4096 + addr) = c1;
      }
    }
    lds_barrier();
    {
      const int rowi = tid >> 7, tt = tid & 127;
      const int pos = tt >> 2, qb = (tt & 3)*32;
      const char* bb = LB + RING1 + rowi*4096;
      const u32 a0 = ((u32)(pos*128 + qb)) ^ (((u32)(pos & 7)) << 4);
      const uint4 v0 = *(const uint4*)(bb + a0);
      const uint4 v1 = *(const uint4*)(bb + (a0 ^ 16u));
      char* dst = (char*)out + ((size_t)((n*HH + h0 + 2*g + rowi)*WW + w0 + pos))*128 + qb;
      *(uint4*)dst = v0;
      *(uint4*)(dst + 16) = v1;
    }
  }

#pragma unroll
  for (int d = 1; d <= 8; d <<= 1) {
#pragma unroll
    for (int r = 0; r < 4; ++r) {
      s4[r] += __shfl_xor(s4[r], d, 64);
      q4[r] += __shfl_xor(q4[r], d, 64);
    }
  }
  if (l15 == 0) {
#pragma unroll
    for (int r = 0; r < 4; ++r) {
      const int co = wv*16 + lq*4 + r;
      ps[(size_t)co*NBC1 + bid] = s4[r];
      pq[(size_t)co*NBC1 + bid] = q4[r];
    }
  }
}

// ---------------- kfin2: finalize two BN stat sets ----------------
__global__ __launch_bounds__(256) void kfin2(
    const float* __restrict__ psA, const float* __restrict__ pqA,
    const float* __restrict__ gA, const float* __restrict__ beA,
    float* __restrict__ AA, float* __restrict__ BA, int cntA,
    const float* __restrict__ psB, const float* __restrict__ pqB,
    const float* __restrict__ gB, const float* __restrict__ beB,
    float* __restrict__ AB, float* __restrict__ BB, int cntB)
{
  const int blk = blockIdx.x;
  const bool second = blk >= 64;
  const int c = blk & 63;
  const float* psx = second ? psB : psA;
  const float* pqx = second ? pqB : pqA;
  const float* g  = second ? gB  : gA;
  const float* be = second ? beB : beA;
  float* A  = second ? AB : AA;
  float* Bc = second ? BB : BA;
  const int cnt = second ? cntB : cntA;

  const int t = threadIdx.x;
  float sv = 0.f, s2 = 0.f;
  const float* pr = psx + (size_t)c*cnt;
  const float* qr = pqx + (size_t)c*cnt;
  for (int k = t; k < cnt; k += 256) { sv += pr[k]; s2 += qr[k]; }
#pragma unroll
  for (int d = 1; d < 64; d <<= 1) { sv += __shfl_xor(sv, d, 64); s2 += __shfl_xor(s2, d, 64); }
  __shared__ float as_[4], aq_[4];
  if ((t & 63) == 0) { as_[t >> 6] = sv; aq_[t >> 6] = s2; }
  __syncthreads();
  if (t == 0) {
    sv = as_[0] + as_[1] + as_[2] + as_[3];
    s2 = aq_[0] + aq_[1] + aq_[2] + aq_[3];
    const float mean = sv / NSTATF;
    const float var = s2 / NSTATF - mean*mean;
    const float istd = rsqrtf(var + 1e-5f);
    const float a = g[c] * istd;
    A[c] = a;
    Bc[c] = be[c] - mean * a;
  }
}

// ---------------- k5: proj MFMA direct-from-global, combine in regs, LDS only for NCHW transpose ----------------
__global__ __launch_bounds__(256) void k5(const u16* __restrict__ y2, const u16* __restrict__ xh,
    const u16* __restrict__ wbp,
    const float* __restrict__ A2, const float* __restrict__ B2c,
    const float* __restrict__ Ap, const float* __restrict__ Bp,
    float* __restrict__ outp)
{
  __shared__ float T[CC*K5S];
  const int tid = threadIdx.x;
  const int lane = tid & 63, wv = tid >> 6;
  const int l15 = lane & 15, lq = lane >> 4;
  const int wt = blockIdx.x, h = blockIdx.y, n = blockIdx.z;
  const int w0 = wt*128;

  short8 wpf[2];
#pragma unroll
  for (int kb = 0; kb < 2; ++kb)
    wpf[kb] = *(const short8*)(wbp + ((size_t)(wv*2 + kb)*64 + lane)*8);

  const int co = wv*16 + lq*4;
  float vA2[4], vB2[4], vAp[4], vBp[4];
#pragma unroll
  for (int r = 0; r < 4; ++r) {
    vA2[r] = A2[co + r]; vB2[r] = B2c[co + r];
    vAp[r] = Ap[co + r]; vBp[r] = Bp[co + r];
  }

  const u16* px = xh + ((size_t)(n*HH + h)*WW + w0)*CC;
  const u16* p2 = y2 + ((size_t)(n*HH + h)*WW + w0)*CC;

#pragma unroll
  for (int t = 0; t < 8; ++t) {
    const int pos = t*16 + l15;
    f32x4 acc = {0.f, 0.f, 0.f, 0.f};
#pragma unroll
    for (int kb = 0; kb < 2; ++kb) {
      const short8 X = *(const short8*)(px + (size_t)pos*CC + kb*32 + lq*8);
      acc = __builtin_amdgcn_mfma_f32_16x16x32_bf16(wpf[kb], X, acc, 0, 0, 0);
    }
    const uint2 y = *(const uint2*)(p2 + (size_t)pos*CC + co);
    float yv[4];
    yv[0] = bf2f((u16)(y.x & 0xFFFFu));
    yv[1] = bf2f((u16)(y.x >> 16));
    yv[2] = bf2f((u16)(y.y & 0xFFFFu));
    yv[3] = bf2f((u16)(y.y >> 16));
#pragma unroll
    for (int r = 0; r < 4; ++r) {
      const float o = fmaxf(yv[r]*vA2[r] + vB2[r] + acc[r]*vAp[r] + vBp[r], 0.f);
      const int c = co + r;
      T[(u32)c*K5S + ((u32)pos ^ (((u32)((c >> 3) & 3)) << 3))] = o;
    }
  }
  __syncthreads();
  // NCHW fp32 write
#pragma unroll
  for (int cc = 0; cc < 16; ++cc) {
    const int c = cc*4 + wv;
    const u32 sw = ((u32)((c >> 3) & 3)) << 3;
    const u32 idx = (u32)c*K5S + (((u32)(lane*2)) ^ sw);
    float2 v;
    v.x = T[idx];
    v.y = T[idx + 1];
    *(float2*)(outp + ((size_t)((n*CC + c)*HH + h))*WW + w0 + lane*2) = v;
  }
}

extern "C" void kernel_launch(void* const* d_in, const int* in_sizes, int n_in,
                              void* d_out, int out_size, void* d_ws, size_t ws_size,
                              hipStream_t stream)
{
  (void)in_sizes; (void)n_in; (void)out_size;
  const float* x   = (const float*)d_in[0];
  const float* w1  = (const float*)d_in[1];
  const float* g1  = (const float*)d_in[3];
  const float* be1 = (const float*)d_in[4];
  const float* w2  = (const float*)d_in[5];
  const float* g2  = (const float*)d_in[7];
  const float* be2 = (const float*)d_in[8];
  const float* wp  = (const float*)d_in[9];
  const float* gp  = (const float*)d_in[11];
  const float* bep = (const float*)d_in[12];

  const size_t TENB = (size_t)2*CC*PLANE*2;   // one bf16 tensor: 67,108,864 B
  char* ws = (char*)d_ws;
  u16* bufA = (u16*)ws;                    // xh (persists through k5)
  u16* bufB = (u16*)(ws + TENB);           // y1
  u16* bufC = (u16*)(ws + TENB*2);         // y2
  char* aux = ws + TENB*3;
  u16* wb1 = (u16*)aux;                              // 73728 B
  u16* wb2 = (u16*)(aux + 73728);                    // 73728 B
  u16* wbp = (u16*)(aux + 147456);                   // 8192 B
  float* ps1 = (float*)(aux + 155648);               // 6 x 64*1024
  float* pq1 = ps1 + 64*NBC1;
  float* psp = pq1 + 64*NBC1;
  float* pqp = psp + 64*NBC1;
  float* ps2 = pqp + 64*NBC1;
  float* pq2 = ps2 + 64*NBC1;
  float* A1  = pq2 + 64*NBC1;
  float* B1  = A1 + 64;
  float* A2  = B1 + 64;
  float* B2c = A2 + 64;
  float* Ap  = B2c + 64;
  float* Bp  = Ap + 64;
  const size_t need = (size_t)(Bp + 64 - (float*)ws) * 4;
  if (ws_size < need) return;

  kprep<<<19, 512, 0, stream>>>(w1, w2, wp, wb1, wb2, wbp);
  k0<<<dim3(2, HH, 2), 256, 0, stream>>>(x, bufA);
  kconv1<<<dim3(16, 32, 2), 256, 0, stream>>>(bufA, wb1, wbp,
                                              bufB, ps1, pq1, psp, pqp);
  kfin2<<<128, 256, 0, stream>>>(ps1, pq1, g1, be1, A1, B1, NBC1,
                                 psp, pqp, gp, bep, Ap, Bp, NBC1);
  kconv2<<<dim3(16, 32, 2), 256, 0, stream>>>(bufB, wb2, A1, B1,
                                              bufC, ps2, pq2);
  kfin2<<<64, 256, 0, stream>>>(ps2, pq2, g2, be2, A2, B2c, NBC1,
                                ps2, pq2, g2, be2, A2, B2c, NBC1);
  k5<<<dim3(4, HH, 2), 256, 0, stream>>>(bufC, bufA, wbp, A2, B2c, Ap, Bp, (float*)d_out);
}

// Round 16
// 209.882 us; speedup vs baseline: 1.0581x; 1.0581x over previous
//
#include <hip/hip_runtime.h>
#include <hip/hip_bf16.h>
#include <stdint.h>

typedef short short8 __attribute__((ext_vector_type(8)));
typedef float f32x4 __attribute__((ext_vector_type(4)));
typedef unsigned int u32;
typedef unsigned short u16;

#define HH 512
#define WW 512
#define CC 64
#define PLANE (HH*WW)
#define NSTATF 524288.0f

// conv geometry (16x16x32, 2-row X-reuse, NSLOT 6)
#define KTW 32
#define HSTR1 560
#define KBSTR1 1120
#define SLOTB1 4480
#define NSLOT 6
#define RING1 (NSLOT*SLOTB1)  // 26880
#define BOUNCE 8192           // 2 rows x 4KB
#define NBC1 1024
#define K5S 132

__device__ __forceinline__ u16 f2bf(float f) {
  __hip_bfloat16 h = __float2bfloat16(f);
  return __builtin_bit_cast(u16, h);
}
__device__ __forceinline__ u32 pk2bf(float a, float b) {
  return (u32)f2bf(a) | ((u32)f2bf(b) << 16);
}
__device__ __forceinline__ float bf2f(u16 u) {
  u32 x = ((u32)u) << 16;
  return __builtin_bit_cast(float, x);
}
__device__ __forceinline__ int m6(int v) {  // v in [0,17] -> v % 6
  v -= (v >= 6) ? 6 : 0;
  v -= (v >= 6) ? 6 : 0;
  return v;
}
// barrier that makes LDS writes visible without draining vmcnt (T4)
__device__ __forceinline__ void lds_barrier() {
  asm volatile("s_waitcnt lgkmcnt(0)" ::: "memory");
  __builtin_amdgcn_s_barrier();
  __builtin_amdgcn_sched_barrier(0);
}

// ---------------- kprep: 16x16x32 fragment layouts for w1, w2, wp ----------------
__global__ __launch_bounds__(512) void kprep(const float* __restrict__ w1,
    const float* __restrict__ w2, const float* __restrict__ wp,
    u16* __restrict__ wb1, u16* __restrict__ wb2, u16* __restrict__ wbp)
{
  const int id = blockIdx.x*512 + threadIdx.x;
  const int lane = id & 63;
  if (id < 9216) {
    const float* w = (id < 4608) ? w1 : w2;
    u16* o = (id < 4608) ? wb1 : wb2;
    const int fid = (id < 4608) ? (id >> 6) : ((id - 4608) >> 6);  // 0..71
    const int ct4 = fid / 18, rem = fid % 18;
    const int tap = rem >> 1, kb = rem & 1;
    const int cout = ct4*16 + (lane & 15);
    const int k0c = kb*32 + (lane >> 4)*8;
    u32 ow[4];
#pragma unroll
    for (int p = 0; p < 4; ++p) {
      ow[p] = pk2bf(w[(size_t)(cout*64 + k0c + p*2)*9 + tap],
                    w[(size_t)(cout*64 + k0c + p*2 + 1)*9 + tap]);
    }
    *(uint4*)(o + ((size_t)fid*64 + lane)*8) = make_uint4(ow[0],ow[1],ow[2],ow[3]);
  } else if (id < 9728) {
    const int fid = (id - 9216) >> 6;     // 0..7
    const int ct4 = fid >> 1, kb = fid & 1;
    const int cout = ct4*16 + (lane & 15);
    const int k0c = kb*32 + (lane >> 4)*8;
    u32 ow[4];
#pragma unroll
    for (int p = 0; p < 4; ++p)
      ow[p] = pk2bf(wp[cout*64 + k0c + p*2], wp[cout*64 + k0c + p*2 + 1]);
    *(uint4*)(wbp + ((size_t)fid*64 + lane)*8) = make_uint4(ow[0],ow[1],ow[2],ow[3]);
  }
}

// ---------------- k0: pure NCHW fp32 -> NHWC bf16 transpose ----------------
__global__ __launch_bounds__(256) void k0(const float* __restrict__ x, u16* __restrict__ xh)
{
  __shared__ __align__(16) u32 Tp[32*260];
  const int tid = threadIdx.x;
  const int wt = blockIdx.x, h = blockIdx.y, n = blockIdx.z;
  const int w0 = wt*256;
  const float* xp = x + (size_t)n*CC*PLANE + (size_t)h*WW + w0;
#pragma unroll
  for (int it = 0; it < 8; ++it) {
    const int j = it*256 + tid;
    const int c2 = j >> 6, w4 = (j & 63) << 2;
    const f32x4 a = *(const f32x4*)(xp + (size_t)(c2*2    )*PLANE + w4);
    const f32x4 b = *(const f32x4*)(xp + (size_t)(c2*2 + 1)*PLANE + w4);
    uint4 o;
    o.x = pk2bf(a[0], b[0]);
    o.y = pk2bf(a[1], b[1]);
    o.z = pk2bf(a[2], b[2]);
    o.w = pk2bf(a[3], b[3]);
    *(uint4*)(Tp + (u32)c2*260 + (u32)(w4 ^ (4*(c2 >> 2)))) = o;
  }
  __syncthreads();
  u16* op = xh + ((size_t)(n*HH + h)*WW + w0)*CC;
#pragma unroll
  for (int it = 0; it < 8; ++it) {
    const int j = it*256 + tid;
    const int w = j >> 3, c8 = j & 7;
    const u32 wsw = (u32)(w ^ (4*c8));
    uint4 o;
    o.x = Tp[(u32)(c8*4 + 0)*260 + wsw];
    o.y = Tp[(u32)(c8*4 + 1)*260 + wsw];
    o.z = Tp[(u32)(c8*4 + 2)*260 + wsw];
    o.w = Tp[(u32)(c8*4 + 3)*260 + wsw];
    *(uint4*)(op + (size_t)w*CC + c8*8) = o;
  }
}

// ---------------- kconv1: 3x3 conv (y1 out) + proj MFMA for STATS ONLY ----------------
__global__ __launch_bounds__(256, 2) void kconv1(const u16* __restrict__ in,
    const u16* __restrict__ wb, const u16* __restrict__ wbp,
    u16* __restrict__ out,
    float* __restrict__ ps, float* __restrict__ pq,
    float* __restrict__ psp, float* __restrict__ pqp)
{
  __shared__ __align__(16) char LB[RING1 + BOUNCE + 512];
  const int tid = threadIdx.x;
  const int lane = tid & 63, wv = tid >> 6;
  const int l15 = lane & 15, lq = lane >> 4;
  const int wt = blockIdx.x, hs = blockIdx.y, n = blockIdx.z;
  const int w0 = wt*KTW, h0 = hs*16;
  const int bid = (n*32 + hs)*16 + wt;

  short8 wfr[18];
#pragma unroll
  for (int f = 0; f < 18; ++f)
    wfr[f] = *(const short8*)(wb + ((size_t)(wv*18 + f)*64 + lane)*8);
  short8 wpf[2];
#pragma unroll
  for (int kb = 0; kb < 2; ++kb)
    wpf[kb] = *(const short8*)(wbp + ((size_t)(wv*2 + kb)*64 + lane)*8);

  float s4[4] = {0,0,0,0}, q4[4] = {0,0,0,0};
  float sp4[4] = {0,0,0,0}, qp4[4] = {0,0,0,0};
  const u16* inb = in + (size_t)n*PLANE*CC;
  const u32 co0 = (u32)((lq >> 1)*KBSTR1 + (lq & 1)*HSTR1);
  const u32 co1 = co0 + 2*KBSTR1;

  auto ld_one = [&](int j, int cl, int c8) -> uint4 {
    const int gh = h0 - 1 + j, gw = w0 - 1 + cl;
    if (((u32)gh < (u32)HH) && ((u32)gw < (u32)WW))
      return *(const uint4*)(inb + ((size_t)gh*WW + gw)*CC + c8*8);
    return make_uint4(0u,0u,0u,0u);
  };
  auto st_one = [&](int slot, int cl, int c8, uint4 v) {
    *(uint4*)(LB + (size_t)slot*SLOTB1 + (c8>>1)*KBSTR1 + (c8&1)*HSTR1 + cl*16) = v;
  };

  for (int idx = tid; idx < 4*272; idx += 256) {
    const int jj = idx / 272, rem = idx - jj*272;
    st_one(jj, rem >> 3, rem & 7, ld_one(jj, rem >> 3, rem & 7));
  }
  __syncthreads();

  uint4 st0, st1, st2;
  auto issue2 = [&](int jb) {
    { const int idx = tid;       const int jj = idx/272, rem = idx - jj*272;
      st0 = ld_one(jb + jj, rem >> 3, rem & 7); }
    { const int idx = 256 + tid; const int jj = idx/272, rem = idx - jj*272;
      st1 = ld_one(jb + jj, rem >> 3, rem & 7); }
    if (tid < 32) { const int idx = 512 + tid; const int jj = idx/272, rem = idx - jj*272;
      st2 = ld_one(jb + jj, rem >> 3, rem & 7); }
  };
  auto write2 = [&](int jb) {
    { const int idx = tid;       const int jj = idx/272, rem = idx - jj*272;
      st_one(m6(jb + jj), rem >> 3, rem & 7, st0); }
    { const int idx = 256 + tid; const int jj = idx/272, rem = idx - jj*272;
      st_one(m6(jb + jj), rem >> 3, rem & 7, st1); }
    if (tid < 32) { const int idx = 512 + tid; const int jj = idx/272, rem = idx - jj*272;
      st_one(m6(jb + jj), rem >> 3, rem & 7, st2); }
  };

  issue2(4);

  for (int g = 0; g < 8; ++g) {
    if (g > 0) write2(2*g + 2);
    lds_barrier();
    if (g < 7) issue2(2*g + 4);

    const char* sb[4];
#pragma unroll
    for (int mi = 0; mi < 4; ++mi)
      sb[mi] = LB + (size_t)m6(2*g + mi)*SLOTB1 + l15*16;
    f32x4 a0t0, a0t1, a1t0, a1t1;
    f32x4 p0t0, p0t1, p1t0, p1t1;
#pragma unroll
    for (int r = 0; r < 4; ++r) {
      a0t0[r]=0.f; a0t1[r]=0.f; a1t0[r]=0.f; a1t1[r]=0.f;
      p0t0[r]=0.f; p0t1[r]=0.f; p1t0[r]=0.f; p1t1[r]=0.f;
    }
#pragma unroll
    for (int t = 0; t < 2; ++t) {
      const int pb = t*16;
#pragma unroll
      for (int kb = 0; kb < 2; ++kb) {
        const u32 ck = kb ? co1 : co0;
#pragma unroll
        for (int mi = 0; mi < 4; ++mi) {
#pragma unroll
          for (int kw = 0; kw < 3; ++kw) {
            const short8 X = *(const short8*)(sb[mi] + ck + (u32)((pb + kw)*16));
            if (mi <= 2) {
              const short8 Wf = wfr[(mi*3 + kw)*2 + kb];
              if (t == 0) a0t0 = __builtin_amdgcn_mfma_f32_16x16x32_bf16(Wf, X, a0t0, 0,0,0);
              else        a0t1 = __builtin_amdgcn_mfma_f32_16x16x32_bf16(Wf, X, a0t1, 0,0,0);
            }
            if (mi >= 1) {
              const short8 Wf = wfr[((mi-1)*3 + kw)*2 + kb];
              if (t == 0) a1t0 = __builtin_amdgcn_mfma_f32_16x16x32_bf16(Wf, X, a1t0, 0,0,0);
              else        a1t1 = __builtin_amdgcn_mfma_f32_16x16x32_bf16(Wf, X, a1t1, 0,0,0);
            }
            if (kw == 1 && mi == 1) {
              if (t == 0) p0t0 = __builtin_amdgcn_mfma_f32_16x16x32_bf16(wpf[kb], X, p0t0, 0,0,0);
              else        p0t1 = __builtin_amdgcn_mfma_f32_16x16x32_bf16(wpf[kb], X, p0t1, 0,0,0);
            }
            if (kw == 1 && mi == 2) {
              if (t == 0) p1t0 = __builtin_amdgcn_mfma_f32_16x16x32_bf16(wpf[kb], X, p1t0, 0,0,0);
              else        p1t1 = __builtin_amdgcn_mfma_f32_16x16x32_bf16(wpf[kb], X, p1t1, 0,0,0);
            }
          }
        }
      }
    }
    {
      const int co = wv*16 + lq*4;
#pragma unroll
      for (int r = 0; r < 4; ++r) {
        s4[r] += a0t0[r] + a0t1[r] + a1t0[r] + a1t1[r];
        q4[r] = fmaf(a0t0[r], a0t0[r], q4[r]);
        q4[r] = fmaf(a0t1[r], a0t1[r], q4[r]);
        q4[r] = fmaf(a1t0[r], a1t0[r], q4[r]);
        q4[r] = fmaf(a1t1[r], a1t1[r], q4[r]);
        sp4[r] += p0t0[r] + p0t1[r] + p1t0[r] + p1t1[r];
        qp4[r] = fmaf(p0t0[r], p0t0[r], qp4[r]);
        qp4[r] = fmaf(p0t1[r], p0t1[r], qp4[r]);
        qp4[r] = fmaf(p1t0[r], p1t0[r], qp4[r]);
        qp4[r] = fmaf(p1t1[r], p1t1[r], qp4[r]);
      }
#pragma unroll
      for (int t = 0; t < 2; ++t) {
        const int pos = t*16 + l15;
        const u32 addr = ((u32)(pos*128 + co*2)) ^ (((u32)(pos & 7)) << 4);
        uint2 c0, c1;
        if (t == 0) {
          c0.x = pk2bf(a0t0[0], a0t0[1]); c0.y = pk2bf(a0t0[2], a0t0[3]);
          c1.x = pk2bf(a1t0[0], a1t0[1]); c1.y = pk2bf(a1t0[2], a1t0[3]);
        } else {
          c0.x = pk2bf(a0t1[0], a0t1[1]); c0.y = pk2bf(a0t1[2], a0t1[3]);
          c1.x = pk2bf(a1t1[0], a1t1[1]); c1.y = pk2bf(a1t1[2], a1t1[3]);
        }
        *(uint2*)(LB + RING1 + 0*4096 + addr) = c0;
        *(uint2*)(LB + RING1 + 1*4096 + addr) = c1;
      }
    }
    lds_barrier();
    {
      const int rowi = tid >> 7, tt = tid & 127;
      const int pos = tt >> 2, qb = (tt & 3)*32;
      const char* bb = LB + RING1 + rowi*4096;
      const u32 a0 = ((u32)(pos*128 + qb)) ^ (((u32)(pos & 7)) << 4);
      const uint4 v0 = *(const uint4*)(bb + a0);
      const uint4 v1 = *(const uint4*)(bb + (a0 ^ 16u));
      char* dst = (char*)out + ((size_t)((n*HH + h0 + 2*g + rowi)*WW + w0 + pos))*128 + qb;
      *(uint4*)dst = v0;
      *(uint4*)(dst + 16) = v1;
    }
  }

#pragma unroll
  for (int d = 1; d <= 8; d <<= 1) {
#pragma unroll
    for (int r = 0; r < 4; ++r) {
      s4[r] += __shfl_xor(s4[r], d, 64);
      q4[r] += __shfl_xor(q4[r], d, 64);
      sp4[r] += __shfl_xor(sp4[r], d, 64);
      qp4[r] += __shfl_xor(qp4[r], d, 64);
    }
  }
  if (l15 == 0) {
#pragma unroll
    for (int r = 0; r < 4; ++r) {
      const int co = wv*16 + lq*4 + r;
      ps[(size_t)co*NBC1 + bid] = s4[r];
      pq[(size_t)co*NBC1 + bid] = q4[r];
      psp[(size_t)co*NBC1 + bid] = sp4[r];
      pqp[(size_t)co*NBC1 + bid] = qp4[r];
    }
  }
}

// ---------------- kconv2: 3x3 conv, 16x16x32, 2-row X-reuse, BN1+ReLU on staging ----------------
__global__ __launch_bounds__(256, 2) void kconv2(const u16* __restrict__ in,
    const u16* __restrict__ wb,
    const float* __restrict__ As, const float* __restrict__ Bs,
    u16* __restrict__ out, float* __restrict__ ps, float* __restrict__ pq)
{
  __shared__ __align__(16) char LB[RING1 + BOUNCE + 512];
  float* sA = (float*)(LB + RING1 + BOUNCE);
  float* sB = sA + 64;
  const int tid = threadIdx.x;
  const int lane = tid & 63, wv = tid >> 6;
  const int l15 = lane & 15, lq = lane >> 4;
  const int wt = blockIdx.x, hs = blockIdx.y, n = blockIdx.z;
  const int w0 = wt*KTW, h0 = hs*16;
  const int bid = (n*32 + hs)*16 + wt;

  if (tid < 64) { sA[tid] = As[tid]; sB[tid] = Bs[tid]; }
  __syncthreads();

  short8 wfr[18];
#pragma unroll
  for (int f = 0; f < 18; ++f)
    wfr[f] = *(const short8*)(wb + ((size_t)(wv*18 + f)*64 + lane)*8);

  float s4[4] = {0,0,0,0}, q4[4] = {0,0,0,0};
  const u16* inb = in + (size_t)n*PLANE*CC;
  const u32 co0 = (u32)((lq >> 1)*KBSTR1 + (lq & 1)*HSTR1);
  const u32 co1 = co0 + 2*KBSTR1;

  auto ld_one = [&](int j, int cl, int c8) -> uint4 {
    const int gh = h0 - 1 + j, gw = w0 - 1 + cl;
    if (((u32)gh < (u32)HH) && ((u32)gw < (u32)WW))
      return *(const uint4*)(inb + ((size_t)gh*WW + gw)*CC + c8*8);
    return make_uint4(0u,0u,0u,0u);
  };
  auto st_one = [&](int slot, int cl, int c8, uint4 v) {
    const u32* uw = (const u32*)&v;
    u32 ow[4];
    const int cb = c8*8;
#pragma unroll
    for (int h2 = 0; h2 < 4; ++h2) {
      float f0 = fmaxf(bf2f((u16)(uw[h2] & 0xFFFFu)) * sA[cb+h2*2]   + sB[cb+h2*2],   0.f);
      float f1 = fmaxf(bf2f((u16)(uw[h2] >> 16))     * sA[cb+h2*2+1] + sB[cb+h2*2+1], 0.f);
      ow[h2] = pk2bf(f0, f1);
    }
    *(uint4*)(LB + (size_t)slot*SLOTB1 + (c8>>1)*KBSTR1 + (c8&1)*HSTR1 + cl*16) =
        make_uint4(ow[0],ow[1],ow[2],ow[3]);
  };

  for (int idx = tid; idx < 4*272; idx += 256) {
    const int jj = idx / 272, rem = idx - jj*272;
    st_one(jj, rem >> 3, rem & 7, ld_one(jj, rem >> 3, rem & 7));
  }
  __syncthreads();

  uint4 st0, st1, st2;
  auto issue2 = [&](int jb) {
    { const int idx = tid;       const int jj = idx/272, rem = idx - jj*272;
      st0 = ld_one(jb + jj, rem >> 3, rem & 7); }
    { const int idx = 256 + tid; const int jj = idx/272, rem = idx - jj*272;
      st1 = ld_one(jb + jj, rem >> 3, rem & 7); }
    if (tid < 32) { const int idx = 512 + tid; const int jj = idx/272, rem = idx - jj*272;
      st2 = ld_one(jb + jj, rem >> 3, rem & 7); }
  };
  auto write2 = [&](int jb) {
    { const int idx = tid;       const int jj = idx/272, rem = idx - jj*272;
      st_one(m6(jb + jj), rem >> 3, rem & 7, st0); }
    { const int idx = 256 + tid; const int jj = idx/272, rem = idx - jj*272;
      st_one(m6(jb + jj), rem >> 3, rem & 7, st1); }
    if (tid < 32) { const int idx = 512 + tid; const int jj = idx/272, rem = idx - jj*272;
      st_one(m6(jb + jj), rem >> 3, rem & 7, st2); }
  };

  issue2(4);

  for (int g = 0; g < 8; ++g) {
    if (g > 0) write2(2*g + 2);
    lds_barrier();
    if (g < 7) issue2(2*g + 4);

    const char* sb[4];
#pragma unroll
    for (int mi = 0; mi < 4; ++mi)
      sb[mi] = LB + (size_t)m6(2*g + mi)*SLOTB1 + l15*16;
    f32x4 a0t0, a0t1, a1t0, a1t1;
#pragma unroll
    for (int r = 0; r < 4; ++r) { a0t0[r]=0.f; a0t1[r]=0.f; a1t0[r]=0.f; a1t1[r]=0.f; }
#pragma unroll
    for (int t = 0; t < 2; ++t) {
      const int pb = t*16;
#pragma unroll
      for (int kb = 0; kb < 2; ++kb) {
        const u32 ck = kb ? co1 : co0;
#pragma unroll
        for (int mi = 0; mi < 4; ++mi) {
#pragma unroll
          for (int kw = 0; kw < 3; ++kw) {
            const short8 X = *(const short8*)(sb[mi] + ck + (u32)((pb + kw)*16));
            if (mi <= 2) {
              const short8 Wf = wfr[(mi*3 + kw)*2 + kb];
              if (t == 0) a0t0 = __builtin_amdgcn_mfma_f32_16x16x32_bf16(Wf, X, a0t0, 0,0,0);
              else        a0t1 = __builtin_amdgcn_mfma_f32_16x16x32_bf16(Wf, X, a0t1, 0,0,0);
            }
            if (mi >= 1) {
              const short8 Wf = wfr[((mi-1)*3 + kw)*2 + kb];
              if (t == 0) a1t0 = __builtin_amdgcn_mfma_f32_16x16x32_bf16(Wf, X, a1t0, 0,0,0);
              else        a1t1 = __builtin_amdgcn_mfma_f32_16x16x32_bf16(Wf, X, a1t1, 0,0,0);
            }
          }
        }
      }
    }
    {
      const int co = wv*16 + lq*4;
#pragma unroll
      for (int r = 0; r < 4; ++r) {
        s4[r] += a0t0[r] + a0t1[r] + a1t0[r] + a1t1[r];
        q4[r] = fmaf(a0t0[r], a0t0[r], q4[r]);
        q4[r] = fmaf(a0t1[r], a0t1[r], q4[r]);
        q4[r] = fmaf(a1t0[r], a1t0[r], q4[r]);
        q4[r] = fmaf(a1t1[r], a1t1[r], q4[r]);
      }
#pragma unroll
      for (int t = 0; t < 2; ++t) {
        const int pos = t*16 + l15;
        const u32 addr = ((u32)(pos*128 + co*2)) ^ (((u32)(pos & 7)) << 4);
        uint2 c0, c1;
        if (t == 0) {
          c0.x = pk2bf(a0t0[0], a0t0[1]); c0.y = pk2bf(a0t0[2], a0t0[3]);
          c1.x = pk2bf(a1t0[0], a1t0[1]); c1.y = pk2bf(a1t0[2], a1t0[3]);
        } else {
          c0.x = pk2bf(a0t1[0], a0t1[1]); c0.y = pk2bf(a0t1[2], a0t1[3]);
          c1.x = pk2bf(a1t1[0], a1t1[1]); c1.y = pk2bf(a1t1[2], a1t1[3]);
        }
        *(uint2*)(LB + RING1 + 0*4096 + addr) = c0;
        *(uint2*)(LB + RING1 + 1*4096 + addr) = c1;
      }
    }
    lds_barrier();
    {
      const int rowi = tid >> 7, tt = tid & 127;
      const int pos = tt >> 2, qb = (tt & 3)*32;
      const char* bb = LB + RING1 + rowi*4096;
      const u32 a0 = ((u32)(pos*128 + qb)) ^ (((u32)(pos & 7)) << 4);
      const uint4 v0 = *(const uint4*)(bb + a0);
      const uint4 v1 = *(const uint4*)(bb + (a0 ^ 16u));
      char* dst = (char*)out + ((size_t)((n*HH + h0 + 2*g + rowi)*WW + w0 + pos))*128 + qb;
      *(uint4*)dst = v0;
      *(uint4*)(dst + 16) = v1;
    }
  }

#pragma unroll
  for (int d = 1; d <= 8; d <<= 1) {
#pragma unroll
    for (int r = 0; r < 4; ++r) {
      s4[r] += __shfl_xor(s4[r], d, 64);
      q4[r] += __shfl_xor(q4[r], d, 64);
    }
  }
  if (l15 == 0) {
#pragma unroll
    for (int r = 0; r < 4; ++r) {
      const int co = wv*16 + lq*4 + r;
      ps[(size_t)co*NBC1 + bid] = s4[r];
      pq[(size_t)co*NBC1 + bid] = q4[r];
    }
  }
}

// ---------------- kfin2: finalize two BN stat sets ----------------
__global__ __launch_bounds__(256) void kfin2(
    const float* __restrict__ psA, const float* __restrict__ pqA,
    const float* __restrict__ gA, const float* __restrict__ beA,
    float* __restrict__ AA, float* __restrict__ BA, int cntA,
    const float* __restrict__ psB, const float* __restrict__ pqB,
    const float* __restrict__ gB, const float* __restrict__ beB,
    float* __restrict__ AB, float* __restrict__ BB, int cntB)
{
  const int blk = blockIdx.x;
  const bool second = blk >= 64;
  const int c = blk & 63;
  const float* psx = second ? psB : psA;
  const float* pqx = second ? pqB : pqA;
  const float* g  = second ? gB  : gA;
  const float* be = second ? beB : beA;
  float* A  = second ? AB : AA;
  float* Bc = second ? BB : BA;
  const int cnt = second ? cntB : cntA;

  const int t = threadIdx.x;
  float sv = 0.f, s2 = 0.f;
  const float* pr = psx + (size_t)c*cnt;
  const float* qr = pqx + (size_t)c*cnt;
  for (int k = t; k < cnt; k += 256) { sv += pr[k]; s2 += qr[k]; }
#pragma unroll
  for (int d = 1; d < 64; d <<= 1) { sv += __shfl_xor(sv, d, 64); s2 += __shfl_xor(s2, d, 64); }
  __shared__ float as_[4], aq_[4];
  if ((t & 63) == 0) { as_[t >> 6] = sv; aq_[t >> 6] = s2; }
  __syncthreads();
  if (t == 0) {
    sv = as_[0] + as_[1] + as_[2] + as_[3];
    s2 = aq_[0] + aq_[1] + aq_[2] + aq_[3];
    const float mean = sv / NSTATF;
    const float var = s2 / NSTATF - mean*mean;
    const float istd = rsqrtf(var + 1e-5f);
    const float a = g[c] * istd;
    A[c] = a;
    Bc[c] = be[c] - mean * a;
  }
}

// ---------------- k5: recompute proj from xh, out = relu(bn2(y2) + bnp(proj)) ----------------
// LDS: T [0,33792) f32 tile; stage aliases T-low [0,16384); bounce [33792,50176); coeffs after.
__global__ __launch_bounds__(256) void k5(const u16* __restrict__ y2, const u16* __restrict__ xh,
    const u16* __restrict__ wbp,
    const float* __restrict__ A2, const float* __restrict__ B2c,
    const float* __restrict__ Ap, const float* __restrict__ Bp,
    float* __restrict__ outp)
{
  __shared__ __align__(16) char L5[50176 + 1024];
  float* T = (float*)L5;
  char* SG = L5;                 // stage region (dead before T is written)
  char* BN = L5 + 33792;         // proj bounce
  float* cA2 = (float*)(L5 + 50176);
  float* cB2 = cA2 + 64;
  float* cAp = cB2 + 64;
  float* cBp = cAp + 64;
  const int tid = threadIdx.x;
  const int lane = tid & 63, wv = tid >> 6;
  const int l15 = lane & 15, lq = lane >> 4;
  const int wt = blockIdx.x, h = blockIdx.y, n = blockIdx.z;
  const int w0 = wt*128;
  if (tid < 64) { cA2[tid] = A2[tid]; cB2[tid] = B2c[tid]; cAp[tid] = Ap[tid]; cBp[tid] = Bp[tid]; }

  short8 wpf[2];
#pragma unroll
  for (int kb = 0; kb < 2; ++kb)
    wpf[kb] = *(const short8*)(wbp + ((size_t)(wv*2 + kb)*64 + lane)*8);

  // phase A: stage xh 128-pos strip (swizzled)
  const u16* px = xh + ((size_t)(n*HH + h)*WW + w0)*CC;
#pragma unroll
  for (int it = 0; it < 4; ++it) {
    const int j = it*256 + tid;
    const int w = j >> 3, c8 = j & 7;
    const uint4 v = *(const uint4*)(px + (size_t)w*CC + c8*8);
    *(uint4*)(SG + (((u32)(w*128 + c8*16)) ^ (((u32)(w & 7)) << 4))) = v;
  }
  __syncthreads();
  // phase B: proj MFMA (wave wv -> couts wv*16+lq*4..+3, 8 pos-tiles) + bounce
  {
    const int co = wv*16 + lq*4;
#pragma unroll
    for (int t = 0; t < 8; ++t) {
      const int pos = t*16 + l15;
      const u32 sw = ((u32)(pos & 7)) << 4;
      f32x4 acc = {0.f, 0.f, 0.f, 0.f};
#pragma unroll
      for (int kb = 0; kb < 2; ++kb) {
        const short8 X = *(const short8*)(SG + (((u32)(pos*128 + kb*64 + lq*16)) ^ sw));
        acc = __builtin_amdgcn_mfma_f32_16x16x32_bf16(wpf[kb], X, acc, 0, 0, 0);
      }
      uint2 d;
      d.x = pk2bf(acc[0], acc[1]);
      d.y = pk2bf(acc[2], acc[3]);
      *(uint2*)(BN + (((u32)(pos*128 + co*2)) ^ sw)) = d;
    }
  }
  __syncthreads();   // bounce visible; stage region now dead -> T may overwrite
  // phase C: combine y2 (global) + proj (LDS) -> T
  const u16* p2 = y2 + ((size_t)(n*HH + h)*WW + w0)*CC;
#pragma unroll
  for (int it = 0; it < 4; ++it) {
    const int j = it*256 + tid;
    const int w = j >> 3, c8 = j & 7;
    const uint4 u2 = *(const uint4*)(p2 + (size_t)w*CC + c8*8);
    const uint4 up = *(const uint4*)(BN + (((u32)(w*128 + c8*16)) ^ (((u32)(w & 7)) << 4)));
    const u32* m2 = (const u32*)&u2;
    const u32* mp = (const u32*)&up;
    const u32 sw = ((u32)(c8 & 3)) << 3;
#pragma unroll
    for (int h2 = 0; h2 < 4; ++h2) {
      const int c = c8*8 + h2*2;
      const float a = bf2f((u16)(m2[h2] & 0xFFFFu)), b = bf2f((u16)(m2[h2] >> 16));
      const float ra = bf2f((u16)(mp[h2] & 0xFFFFu)), rb = bf2f((u16)(mp[h2] >> 16));
      const u32 wsw = (u32)w ^ sw;
      T[(u32)(c    )*K5S + wsw] = fmaxf(a*cA2[c]   + cB2[c]   + ra*cAp[c]   + cBp[c],   0.f);
      T[(u32)(c + 1)*K5S + wsw] = fmaxf(b*cA2[c+1] + cB2[c+1] + rb*cAp[c+1] + cBp[c+1], 0.f);
    }
  }
  __syncthreads();
  // phase D: NCHW fp32 write
#pragma unroll
  for (int cc = 0; cc < 16; ++cc) {
    const int c = cc*4 + wv;
    const u32 sw = ((u32)((c >> 3) & 3)) << 3;
    const u32 idx = (u32)c*K5S + (((u32)(lane*2)) ^ sw);
    float2 v;
    v.x = T[idx];
    v.y = T[idx + 1];
    *(float2*)(outp + ((size_t)((n*CC + c)*HH + h))*WW + w0 + lane*2) = v;
  }
}

extern "C" void kernel_launch(void* const* d_in, const int* in_sizes, int n_in,
                              void* d_out, int out_size, void* d_ws, size_t ws_size,
                              hipStream_t stream)
{
  (void)in_sizes; (void)n_in; (void)out_size;
  const float* x   = (const float*)d_in[0];
  const float* w1  = (const float*)d_in[1];
  const float* g1  = (const float*)d_in[3];
  const float* be1 = (const float*)d_in[4];
  const float* w2  = (const float*)d_in[5];
  const float* g2  = (const float*)d_in[7];
  const float* be2 = (const float*)d_in[8];
  const float* wp  = (const float*)d_in[9];
  const float* gp  = (const float*)d_in[11];
  const float* bep = (const float*)d_in[12];

  const size_t TENB = (size_t)2*CC*PLANE*2;   // one bf16 tensor: 67,108,864 B
  char* ws = (char*)d_ws;
  u16* bufA = (u16*)ws;                    // xh (persists through k5)
  u16* bufB = (u16*)(ws + TENB);           // y1
  u16* bufC = (u16*)(ws + TENB*2);         // y2
  char* aux = ws + TENB*3;
  u16* wb1 = (u16*)aux;                              // 73728 B
  u16* wb2 = (u16*)(aux + 73728);                    // 73728 B
  u16* wbp = (u16*)(aux + 147456);                   // 8192 B
  float* ps1 = (float*)(aux + 155648);               // 6 x 64*1024
  float* pq1 = ps1 + 64*NBC1;
  float* psp = pq1 + 64*NBC1;
  float* pqp = psp + 64*NBC1;
  float* ps2 = pqp + 64*NBC1;
  float* pq2 = ps2 + 64*NBC1;
  float* A1  = pq2 + 64*NBC1;
  float* B1  = A1 + 64;
  float* A2  = B1 + 64;
  float* B2c = A2 + 64;
  float* Ap  = B2c + 64;
  float* Bp  = Ap + 64;
  const size_t need = (size_t)(Bp + 64 - (float*)ws) * 4;
  if (ws_size < need) return;

  kprep<<<19, 512, 0, stream>>>(w1, w2, wp, wb1, wb2, wbp);
  k0<<<dim3(2, HH, 2), 256, 0, stream>>>(x, bufA);
  kconv1<<<dim3(16, 32, 2), 256, 0, stream>>>(bufA, wb1, wbp,
                                              bufB, ps1, pq1, psp, pqp);
  kfin2<<<128, 256, 0, stream>>>(ps1, pq1, g1, be1, A1, B1, NBC1,
                                 psp, pqp, gp, bep, Ap, Bp, NBC1);
  kconv2<<<dim3(16, 32, 2), 256, 0, stream>>>(bufB, wb2, A1, B1,
                                              bufC, ps2, pq2);
  kfin2<<<64, 256, 0, stream>>>(ps2, pq2, g2, be2, A2, B2c, NBC1,
                                ps2, pq2, g2, be2, A2, B2c, NBC1);
  k5<<<dim3(4, HH, 2), 256, 0, stream>>>(bufC, bufA, wbp, A2, B2c, Ap, Bp, (float*)d_out);
}